// Round 9
// baseline (601.482 us; speedup 1.0000x reference)
//
#include <hip/hip_runtime.h>

#define BATCH   32
#define SEQ     2048
#define IN_DIM  32
#define HID     512
#define STATE   64
#define NLAYERS 4
#define NTOK    (BATCH*SEQ)          // 65536
#define EPS     1e-5f
#define KTAN    2.8853900817779268f  // 2*log2(e)

typedef __attribute__((ext_vector_type(8))) short short8v;
typedef __attribute__((ext_vector_type(4))) float f32x4;

__device__ __forceinline__ float fast_exp2(float x){ return __builtin_amdgcn_exp2f(x); }
__device__ __forceinline__ float fast_rcp(float x){ return __builtin_amdgcn_rcpf(x); }
__device__ __forceinline__ short f2bf(float f){           // RNE float->bf16
  unsigned u = __float_as_uint(f);
  unsigned r = (u + 0x7FFF + ((u>>16)&1)) >> 16;
  return (short)r;
}
__device__ __forceinline__ float bf2f(short s){
  return __uint_as_float(((unsigned)(unsigned short)s) << 16);
}

// ---------------------------------------------------------------------------
// All precompute, 38 blocks x 256 threads.
//  blk 0..3 : layer l: ApT[s][j]=bf16(g*A), Cb[j][s]=bf16(C), GA, BA
//  blk 4..35: k=blk-4: WA1[k][s]=sum_j Win[k][j]g0[j]A0[j][s] -> bf16 hi/lo [s][k]
//  blk 36   : binA[s] = sum_j bin[j] g0[j] A0[j][s]  (fp32)
//  blk 37   : WinT[c][k] = bf16(Win[k][c])
__global__ __launch_bounds__(256) void k_prep(
    const float* __restrict__ A, const float* __restrict__ g,
    const float* __restrict__ b, const float* __restrict__ Win,
    const float* __restrict__ bin, const float* __restrict__ C,
    short* __restrict__ ApT, float* __restrict__ GA, float* __restrict__ BA,
    short* __restrict__ WA1Th, short* __restrict__ WA1Tl,
    float* __restrict__ binA, short* __restrict__ Cb, short* __restrict__ WinT)
{
  __shared__ float red[4][64], red2[4][64];
  int tid = threadIdx.x;
  int s = tid & 63, part = tid >> 6;
  int blk = blockIdx.x;
  if (blk < NLAYERS){
    int l = blk;
    const float* Al = A + l*HID*STATE;
    const float* Cl = C + l*HID*STATE;
    const float* gl = g + l*HID;
    const float* bl = b + l*HID;
    float ga=0.f, ba=0.f;
    for (int j=part*128; j<(part+1)*128; ++j){
      float a  = Al[j*STATE+s];
      float ap = gl[j]*a;
      ApT[l*HID*STATE + s*HID + j] = f2bf(ap);      // [s][j] bf16
      Cb[l*HID*STATE + j*STATE + s] = f2bf(Cl[j*STATE+s]);
      ga += ap; ba = fmaf(bl[j], a, ba);
    }
    red[part][s]=ga; red2[part][s]=ba;
    __syncthreads();
    if (tid < 64){
      GA[l*STATE+s] = red[0][s]+red[1][s]+red[2][s]+red[3][s];
      BA[l*STATE+s] = red2[0][s]+red2[1][s]+red2[2][s]+red2[3][s];
    }
  } else if (blk < NLAYERS+32){
    int k = blk - NLAYERS;            // 0..31
    const float* w = Win + k*HID;
    float acc = 0.f;
    for (int j=part*128; j<(part+1)*128; ++j)
      acc = fmaf(w[j], g[j]*A[j*STATE+s], acc);     // layer-0 slices
    red[part][s] = acc;
    __syncthreads();
    if (tid < 64){
      float v = red[0][s]+red[1][s]+red[2][s]+red[3][s];
      short hi = f2bf(v);
      WA1Th[s*IN_DIM + k] = hi;
      WA1Tl[s*IN_DIM + k] = f2bf(v - bf2f(hi));
    }
  } else if (blk == NLAYERS+32){
    float acc = 0.f;
    for (int j=part*128; j<(part+1)*128; ++j)
      acc = fmaf(bin[j], g[j]*A[j*STATE+s], acc);
    red[part][s] = acc;
    __syncthreads();
    if (tid < 64) binA[s] = red[0][s]+red[1][s]+red[2][s]+red[3][s];
  } else {
    for (int e = tid; e < HID*IN_DIM; e += 256){
      int cc = e >> 5, k = e & 31;
      WinT[cc*IN_DIM + k] = f2bf(Win[k*HID + cc]);
    }
  }
}

// ---------------------------------------------------------------------------
// Fused input via MFMA: h(bf16) = x@Win + bin; layer-0 LN stats; U_0 via
// 3-term bf16-split x@WA1 closed form. BM=64, 4 waves, grid 1024.
// MFMA 16x16x32: A[row][k] row=lane&15, k=(lane>>4)*8..+7; B[col][k] same;
// D: col=lane&15, row=(lane>>4)*4+reg.
__global__ __launch_bounds__(256) void k_input(const float* __restrict__ x,
    const short* __restrict__ WinT, const float* __restrict__ bin,
    const short* __restrict__ WA1Th, const short* __restrict__ WA1Tl,
    const float* __restrict__ binA,
    const float* __restrict__ GA0, const float* __restrict__ BA0,
    short* __restrict__ h, float* __restrict__ U, float2* __restrict__ stats)
{
  __shared__ __align__(16) short xhi[64][72];
  __shared__ __align__(16) short xlo[64][72];
  int m0 = blockIdx.x * 64;
  int tid = threadIdx.x;
  int w = tid >> 6, lane = tid & 63;
  int c = lane & 15, q = lane >> 4;
  #pragma unroll
  for (int i=0;i<8;i++){
    int idx = tid + i*256;            // 0..2047
    int row = idx >> 5, k = idx & 31;
    float v = x[(size_t)(m0+row)*IN_DIM + k];
    short hi = f2bf(v);
    xhi[row][k] = hi;
    xlo[row][k] = f2bf(v - bf2f(hi));
  }
  __syncthreads();
  short8v ah = *reinterpret_cast<const short8v*>(&xhi[w*16 + c][q*8]);
  short8v al = *reinterpret_cast<const short8v*>(&xlo[w*16 + c][q*8]);
  float sum[4]={0.f,0.f,0.f,0.f}, sq[4]={0.f,0.f,0.f,0.f};
  // Y = x@Win + bin over 8 chunks of 64 cols
  for (int jc=0; jc<HID; jc+=64){
    f32x4 acc[4];
    #pragma unroll
    for (int t=0;t<4;t++){
      short8v bv = *reinterpret_cast<const short8v*>(&WinT[(size_t)(jc + t*16 + c)*IN_DIM + q*8]);
      f32x4 a = {0.f,0.f,0.f,0.f};
      acc[t] = __builtin_amdgcn_mfma_f32_16x16x32_bf16(ah, bv, a, 0, 0, 0);
    }
    #pragma unroll
    for (int t=0;t<4;t++){
      int col = jc + t*16 + c;
      float bj = bin[col];
      #pragma unroll
      for (int r=0;r<4;r++){
        int m = m0 + w*16 + q*4 + r;
        float o = acc[t][r] + bj;
        h[(size_t)m*HID + col] = f2bf(o);
        sum[r] += o; sq[r] += o*o;
      }
    }
  }
  // stats (16-lane xor butterfly -> all lanes)
  float mu[4], rs[4];
  #pragma unroll
  for (int r=0;r<4;r++){
    float s_ = sum[r], qq = sq[r];
    #pragma unroll
    for (int off=1; off<16; off<<=1){
      s_ += __shfl_xor(s_, off);
      qq += __shfl_xor(qq, off);
    }
    mu[r] = s_*(1.f/HID);
    float var = qq*(1.f/HID) - mu[r]*mu[r];
    rs[r] = rsqrtf(fmaxf(var,0.f)+EPS);
    if (c==0) stats[m0 + w*16 + q*4 + r] = make_float2(mu[r], rs[r]);
  }
  // U0 = KTAN*(rs*(x@WA1 + binA - mu*GA0) + BA0) + KTAN, 3-term split product
  #pragma unroll
  for (int t=0;t<4;t++){
    short8v bh = *reinterpret_cast<const short8v*>(&WA1Th[(size_t)(t*16 + c)*IN_DIM + q*8]);
    short8v blv = *reinterpret_cast<const short8v*>(&WA1Tl[(size_t)(t*16 + c)*IN_DIM + q*8]);
    f32x4 a = {0.f,0.f,0.f,0.f};
    a = __builtin_amdgcn_mfma_f32_16x16x32_bf16(ah, bh, a, 0, 0, 0);
    a = __builtin_amdgcn_mfma_f32_16x16x32_bf16(al, bh, a, 0, 0, 0);
    a = __builtin_amdgcn_mfma_f32_16x16x32_bf16(ah, blv, a, 0, 0, 0);
    int s = t*16 + c;
    float ga = GA0[s], ba = BA0[s], bA = binA[s];
    #pragma unroll
    for (int r=0;r<4;r++){
      int m = m0 + w*16 + q*4 + r;
      float u = a[r] + bA;
      U[(size_t)m*STATE + s] = fmaf(KTAN, rs[r]*(u - mu[r]*ga) + ba, KTAN);
    }
  }
}

// ---------------------------------------------------------------------------
// Sequential recurrence, 1 wave per batch element, register-resident chain,
// 32-deep global prefetch; H written bf16.
__global__ __launch_bounds__(64) void k_scan(const float* __restrict__ U,
                                             short* __restrict__ H)
{
  int b = blockIdx.x;
  int s = threadIdx.x;
  const float* Up = U + (size_t)b*SEQ*STATE + s;
  short* Hp = H + (size_t)b*SEQ*STATE + s;
  float r = 0.5f;                      // tanh(0) -> r = 0.5
  float cur[32], nxt[32];
  #pragma unroll
  for (int i=0;i<32;i++) cur[i] = Up[i*STATE];
  for (int t0=0; t0<SEQ; t0+=32){
    bool has_next = (t0+32 < SEQ);
    if (has_next){
      #pragma unroll
      for (int i=0;i<32;i++) nxt[i] = Up[(t0+32+i)*STATE];
    }
    #pragma unroll
    for (int i=0;i<32;i++){
      float e = fast_exp2(fmaf(-2.f*KTAN, r, cur[i]));
      r = fast_rcp(1.f + e);
      Hp[(t0+i)*STATE] = f2bf(fmaf(-2.f, r, 1.f));
    }
    if (has_next){
      #pragma unroll
      for (int i=0;i<32;i++) cur[i] = nxt[i];
    }
  }
}

// ---------------------------------------------------------------------------
// Fused Y epilogue + next-layer U GEMM, all bf16 MFMA.
//  h += H@C^T + LN(h)*D  (RMW bf16); stats_out; if has_next:
//  U[m][s] = KTAN*(rs*(h_new@Ap' - mu*GA) + BA) + KTAN via per-chunk MFMA
//  on the wave-private h_new LDS tile (uacc accumulated raw, affine at end).
__global__ __launch_bounds__(256) void k_yep3(
    short* __restrict__ h, const short* __restrict__ Hg,
    const short* __restrict__ Cb, const float* __restrict__ Dl,
    const float* __restrict__ gl, const float* __restrict__ bl,
    const float2* __restrict__ stats_in, float2* __restrict__ stats_out,
    const short* __restrict__ ApTn, const float* __restrict__ GAn,
    const float* __restrict__ BAn, float* __restrict__ U, int has_next)
{
  __shared__ __align__(16) short Hsh[64][72];     // 9.2 KB
  __shared__ __align__(16) short Csh[64][72];     // 9.2 KB
  __shared__ __align__(16) short Ash[64][72];     // 9.2 KB
  __shared__ __align__(16) short hn[4][16][72];   // 9.2 KB, wave-private tiles
  int m0 = blockIdx.x * 64;
  int tid = threadIdx.x;
  int w = tid >> 6, lane = tid & 63;
  int c = lane & 15, q = lane >> 4;
  #pragma unroll
  for (int p=0;p<2;p++){
    int idx = tid + p*256;
    int row = idx >> 3, kb = idx & 7;
    *reinterpret_cast<short8v*>(&Hsh[row][kb*8]) =
      *reinterpret_cast<const short8v*>(&Hg[(size_t)(m0+row)*STATE + kb*8]);
  }
  float mu[4], rs[4];
  #pragma unroll
  for (int r=0;r<4;r++){
    float2 s2 = stats_in[m0 + w*16 + q*4 + r];
    mu[r]=s2.x; rs[r]=s2.y;
  }
  float sum[4]={0.f,0.f,0.f,0.f}, sq[4]={0.f,0.f,0.f,0.f};
  f32x4 uacc[4] = {{0.f,0.f,0.f,0.f},{0.f,0.f,0.f,0.f},{0.f,0.f,0.f,0.f},{0.f,0.f,0.f,0.f}};
  __syncthreads();
  short8v a0 = *reinterpret_cast<const short8v*>(&Hsh[w*16 + c][q*8]);
  short8v a1 = *reinterpret_cast<const short8v*>(&Hsh[w*16 + c][32 + q*8]);
  for (int jc=0; jc<HID; jc+=64){
    #pragma unroll
    for (int p=0;p<2;p++){
      int idx = tid + p*256;
      int col = idx >> 3, kb = idx & 7;
      *reinterpret_cast<short8v*>(&Csh[col][kb*8]) =
        *reinterpret_cast<const short8v*>(&Cb[(size_t)(jc+col)*STATE + kb*8]);
    }
    if (has_next){
      #pragma unroll
      for (int p=0;p<2;p++){
        int idx = tid + p*256;
        int sr = idx >> 3, jb = idx & 7;
        *reinterpret_cast<short8v*>(&Ash[sr][jb*8]) =
          *reinterpret_cast<const short8v*>(&ApTn[(size_t)sr*HID + jc + jb*8]);
      }
    }
    __syncthreads();
    f32x4 acc[4];
    #pragma unroll
    for (int t=0;t<4;t++){
      short8v b0 = *reinterpret_cast<const short8v*>(&Csh[t*16 + c][q*8]);
      short8v b1 = *reinterpret_cast<const short8v*>(&Csh[t*16 + c][32 + q*8]);
      f32x4 a = {0.f,0.f,0.f,0.f};
      a = __builtin_amdgcn_mfma_f32_16x16x32_bf16(a0, b0, a, 0, 0, 0);
      a = __builtin_amdgcn_mfma_f32_16x16x32_bf16(a1, b1, a, 0, 0, 0);
      acc[t] = a;
    }
    #pragma unroll
    for (int t=0;t<4;t++){
      int col = jc + t*16 + c;
      float gj = gl[col], bj = bl[col], dj = Dl[col];
      #pragma unroll
      for (int r=0;r<4;r++){
        int m = m0 + w*16 + q*4 + r;
        float hv = bf2f(h[(size_t)m*HID + col]);
        float o = hv + acc[t][r] + fmaf((hv-mu[r])*rs[r], gj, bj)*dj;
        short ob = f2bf(o);
        h[(size_t)m*HID + col] = ob;
        hn[w][q*4+r][t*16+c] = ob;
        sum[r] += o; sq[r] += o*o;
      }
    }
    if (has_next){
      // wave-private: rows of hn[w] were written by this wave only
      short8v u0 = *reinterpret_cast<const short8v*>(&hn[w][c][q*8]);
      short8v u1 = *reinterpret_cast<const short8v*>(&hn[w][c][32 + q*8]);
      #pragma unroll
      for (int t=0;t<4;t++){
        short8v b0 = *reinterpret_cast<const short8v*>(&Ash[t*16 + c][q*8]);
        short8v b1 = *reinterpret_cast<const short8v*>(&Ash[t*16 + c][32 + q*8]);
        uacc[t] = __builtin_amdgcn_mfma_f32_16x16x32_bf16(u0, b0, uacc[t], 0, 0, 0);
        uacc[t] = __builtin_amdgcn_mfma_f32_16x16x32_bf16(u1, b1, uacc[t], 0, 0, 0);
      }
    }
    __syncthreads();
  }
  float mu2[4], rs2[4];
  #pragma unroll
  for (int r=0;r<4;r++){
    float s_ = sum[r], qq = sq[r];
    #pragma unroll
    for (int off=1; off<16; off<<=1){
      s_ += __shfl_xor(s_, off);
      qq += __shfl_xor(qq, off);
    }
    mu2[r] = s_*(1.f/HID);
    float var = qq*(1.f/HID) - mu2[r]*mu2[r];
    rs2[r] = rsqrtf(fmaxf(var,0.f)+EPS);
    if (c==0) stats_out[m0 + w*16 + q*4 + r] = make_float2(mu2[r], rs2[r]);
  }
  if (has_next){
    #pragma unroll
    for (int t=0;t<4;t++){
      int s = t*16 + c;
      float ga = GAn[s], ba = BAn[s];
      #pragma unroll
      for (int r=0;r<4;r++){
        int m = m0 + w*16 + q*4 + r;
        U[(size_t)m*STATE + s] = fmaf(KTAN, rs2[r]*(uacc[t][r] - mu2[r]*ga) + ba, KTAN);
      }
    }
  }
}

// ---------------------------------------------------------------------------
__global__ __launch_bounds__(256) void k_head(const short* __restrict__ h,
   const float2* __restrict__ stats, const float* __restrict__ ng, const float* __restrict__ nb,
   const float* __restrict__ W1, const float* __restrict__ b1,
   const float* __restrict__ W2, const float* __restrict__ b2,
   float* __restrict__ out)
{
  int bb = blockIdx.x;
  int m = bb*SEQ + (SEQ-1);
  int tid = threadIdx.x;
  __shared__ float xs[HID];
  __shared__ float red[8];
  float2 st = stats[m];
  #pragma unroll
  for (int i=0;i<2;i++){
    int j = tid + i*256;
    float v = bf2f(h[(size_t)m*HID + j]);
    xs[j] = fmaf((v - st.x)*st.y, ng[j], nb[j]);
  }
  __syncthreads();
  float acc = b1[tid];
  #pragma unroll 8
  for (int j=0;j<HID;j++) acc = fmaf(xs[j], W1[j*(HID/2) + tid], acc);
  float ge = 0.5f*acc*(1.f + erff(acc*0.70710678118654752f));
  float p0 = ge*W2[tid*2+0];
  float p1 = ge*W2[tid*2+1];
  #pragma unroll
  for (int off=32; off; off>>=1){ p0 += __shfl_down(p0, off); p1 += __shfl_down(p1, off); }
  int wid = tid>>6;
  if ((tid&63)==0){ red[wid*2]=p0; red[wid*2+1]=p1; }
  __syncthreads();
  if (tid==0){
    float o0=b2[0], o1=b2[1];
    #pragma unroll
    for (int w=0;w<4;w++){ o0+=red[w*2]; o1+=red[w*2+1]; }
    out[bb*2+0]=o0; out[bb*2+1]=o1;
  }
}

// ---------------------------------------------------------------------------
extern "C" void kernel_launch(void* const* d_in, const int* in_sizes, int n_in,
                              void* d_out, int out_size, void* d_ws, size_t ws_size,
                              hipStream_t stream)
{
  (void)in_sizes; (void)n_in; (void)out_size; (void)ws_size;
  const float* x   = (const float*)d_in[0];
  const float* Win = (const float*)d_in[1];
  const float* bin = (const float*)d_in[2];
  const float* A   = (const float*)d_in[3];
  const float* C   = (const float*)d_in[4];
  const float* Dv  = (const float*)d_in[5];
  const float* lng = (const float*)d_in[6];
  const float* lnb = (const float*)d_in[7];
  const float* ng  = (const float*)d_in[8];
  const float* nb  = (const float*)d_in[9];
  const float* W1  = (const float*)d_in[10];
  const float* b1  = (const float*)d_in[11];
  const float* W2  = (const float*)d_in[12];
  const float* b2  = (const float*)d_in[13];
  float* out = (float*)d_out;
  char* ws = (char*)d_ws;
  short*  hb   = (short*)(ws + 0);                       //  67,108,864 (bf16)
  float*  Ubuf = (float*)(ws + (size_t)67108864);        //  16,777,216
  short*  Hbuf = (short*)(ws + (size_t)83886080);        //   8,388,608 (bf16)
  float2* st0  = (float2*)(ws + (size_t)92274688);       //     524,288
  float2* st1  = (float2*)(ws + (size_t)92798976);       //     524,288
  short*  ApT  = (short*)(ws + (size_t)93323264);        //     262,144 (bf16)
  float*  GAb  = (float*)(ws + (size_t)93585408);        //       1,024
  float*  BAb  = (float*)(ws + (size_t)93586432);        //       1,024
  float*  binAb= (float*)(ws + (size_t)93587456);        //         256
  short*  Cb   = (short*)(ws + (size_t)93587712);        //     262,144 (bf16)
  short*  WinT = (short*)(ws + (size_t)93849856);        //      32,768 (bf16)
  short*  WA1Th= (short*)(ws + (size_t)93882624);        //       4,096 (bf16)
  short*  WA1Tl= (short*)(ws + (size_t)93886720);        //       4,096 (bf16)

  hipLaunchKernelGGL(k_prep,  dim3(38), dim3(256), 0, stream,
      A, lng, lnb, Win, bin, C, ApT, GAb, BAb, WA1Th, WA1Tl, binAb, Cb, WinT);
  hipLaunchKernelGGL(k_input, dim3(NTOK/64), dim3(256), 0, stream,
      x, WinT, bin, WA1Th, WA1Tl, binAb, GAb, BAb, hb, Ubuf, st0);
  float2* scur = st0; float2* snxt = st1;
  for (int l=0; l<NLAYERS; ++l){
    int has_next = (l < NLAYERS-1) ? 1 : 0;
    int ln = has_next ? (l+1) : 0;
    hipLaunchKernelGGL(k_scan, dim3(BATCH),   dim3(64),  0, stream, Ubuf, Hbuf);
    hipLaunchKernelGGL(k_yep3, dim3(NTOK/64), dim3(256), 0, stream,
        hb, Hbuf, Cb + l*HID*STATE, Dv + l*HID, lng + l*HID, lnb + l*HID,
        scur, snxt, ApT + ln*HID*STATE, GAb + ln*STATE, BAb + ln*STATE,
        Ubuf, has_next);
    float2* t = scur; scur = snxt; snxt = t;
  }
  hipLaunchKernelGGL(k_head, dim3(BATCH), dim3(256), 0, stream,
      hb, scur, ng, nb, W1, b1, W2, b2, out);
}